// Round 2
// baseline (269.742 us; speedup 1.0000x reference)
//
#include <hip/hip_runtime.h>

#define N_NODES 4096
#define EPS 0.005f
#define TH0 0.4f
#define TH1 0.24f
#define TH2 0.144f
#define TH3 0.0864f
#define JTILE 512
#define NTILES (N_NODES / JTILE)
#define RCAP 80      // fixed per-row slot capacity (mean deg 32, P(>80)~1e-13)
#define CPAD 16      // one counter per 64B line -> no cross-XCD line ping-pong

typedef float v4f __attribute__((ext_vector_type(4)));
typedef unsigned int u32x4 __attribute__((ext_vector_type(4)));

// ws layout (byte offsets):
//   0      counts int[4096*16]         256KB \ one contiguous memset (2816KB)
//   256K   pairs  int2[4096*RCAP]      2.5MB / pads col=0,val=0 -> fma no-op
//   4M     m2     bf16[N*N]            32MB dense thresholded A@A
// NOTE: out_kernel edge prefetch may overshoot a row's 640B pair strip by up
// to 64B (next row / tail pad region, still inside ws) — loaded, never used.

static __device__ __forceinline__ float lo16(unsigned int u) {
    return __uint_as_float(u << 16);
}
static __device__ __forceinline__ float hi16(unsigned int u) {
    return __uint_as_float(u & 0xffff0000u);
}

static __device__ __forceinline__ unsigned short f2bf(float f) {
    union { float f; unsigned int i; } x;
    x.f = f;
    unsigned int r = x.i + 0x7fff + ((x.i >> 16) & 1u);  // RNE; finite >=0
    return (unsigned short)(r >> 16);
}

// one pass: bin edges into fixed-stride packed (col,val) slots
__global__ void scatter_kernel(const int* __restrict__ idx,
                               const float* __restrict__ attr, int E,
                               int* __restrict__ counts, int2* __restrict__ pairs) {
    int e = blockIdx.x * blockDim.x + threadIdx.x;
    if (e < E) {
        int s = idx[e];
        int d = idx[e + E];
        float a = attr[e];
        int pos = atomicAdd(&counts[s * CPAD], 1);
        if (pos < RCAP) pairs[s * RCAP + pos] = make_int2(d, __float_as_int(a));
    }
}

// M2 = thr(A@A) bf16. One block per row, full-row 16KB LDS accumulator.
// 32 groups x 8 lanes; fan-out list walked in 32-slot rounds of 4 INDEPENDENT
// loads (chain depth 4 -> 1). Slots in [fn,RCAP) are zero-pads -> no-op adds.
__global__ __launch_bounds__(256)
void m2_kernel(const int* __restrict__ counts, const int2* __restrict__ pairs,
               unsigned short* __restrict__ m2) {
    __shared__ float acc[N_NODES];
    __shared__ int   kcol[RCAP];
    __shared__ float kval[RCAP];
    __shared__ int   kcnt[RCAP];
    int i = blockIdx.x;
    int t = threadIdx.x;
    float4 z = make_float4(0.f, 0.f, 0.f, 0.f);
    for (int j4 = t; j4 < N_NODES / 4; j4 += 256) ((float4*)acc)[j4] = z;
    int cnt = min(counts[i * CPAD], RCAP);
    if (t < cnt) {
        int2 p = pairs[i * RCAP + t];
        kcol[t] = p.x;
        kval[t] = __int_as_float(p.y);
        kcnt[t] = min(counts[p.x * CPAD], RCAP);
    }
    __syncthreads();
    int gid = t >> 3, gl = t & 7;            // 32 groups x 8 lanes
    int2 zp = make_int2(0, 0);
    for (int q = gid; q < cnt; q += 32) {
        float a = kval[q];
        int fb = kcol[q] * RCAP;
        int fn = kcnt[q];
        for (int f0 = gl; f0 < fn; f0 += 32) {
            int i1 = f0 + 8, i2 = f0 + 16, i3 = f0 + 24;
            // 4 independent loads issued before any atomic; masked -> (0,0)
            int2 p0 = pairs[fb + f0];
            int2 p1 = (i1 < fn) ? pairs[fb + i1] : zp;
            int2 p2 = (i2 < fn) ? pairs[fb + i2] : zp;
            int2 p3 = (i3 < fn) ? pairs[fb + i3] : zp;
            unsafeAtomicAdd(&acc[p0.x], a * __int_as_float(p0.y));
            unsafeAtomicAdd(&acc[p1.x], a * __int_as_float(p1.y));
            unsafeAtomicAdd(&acc[p2.x], a * __int_as_float(p2.y));
            unsafeAtomicAdd(&acc[p3.x], a * __int_as_float(p3.y));
        }
    }
    __syncthreads();
    size_t rb = (size_t)i * N_NODES;
    for (int j4 = t; j4 < N_NODES / 4; j4 += 256) {
        float4 v = ((const float4*)acc)[j4];
        ushort4 r;
        r.x = (v.x >= EPS) ? f2bf(v.x) : (unsigned short)0;
        r.y = (v.y >= EPS) ? f2bf(v.y) : (unsigned short)0;
        r.z = (v.z >= EPS) ? f2bf(v.z) : (unsigned short)0;
        r.w = (v.w >= EPS) ? f2bf(v.w) : (unsigned short)0;
        ((ushort4*)(m2 + rb))[j4] = r;
    }
}

// out[i, jb:jb+512] = TH0*P0 + TH1*A + TH2*M2 + TH3*thr(A @ M2)  — fused.
// Minimal-state software pipeline: ONE edge-quad prefetch buffer (n0..n3,
// one batch ahead) + U ping-pong (uA/uB). Steady state has zero exposed
// latency: EXTR waits on edges issued a full consume (512cy) earlier;
// CONSUME8 waits vmcnt(12) on U issued one phase earlier. ~120 live VGPRs.
#define ACC8(uu, aa)                                \
        acc0.x = fmaf(aa, lo16(uu.x), acc0.x);      \
        acc0.y = fmaf(aa, hi16(uu.x), acc0.y);      \
        acc0.z = fmaf(aa, lo16(uu.y), acc0.z);      \
        acc0.w = fmaf(aa, hi16(uu.y), acc0.w);      \
        acc1.x = fmaf(aa, lo16(uu.z), acc1.x);      \
        acc1.y = fmaf(aa, hi16(uu.z), acc1.y);      \
        acc1.z = fmaf(aa, lo16(uu.w), acc1.z);      \
        acc1.w = fmaf(aa, hi16(uu.w), acc1.w);

#define EXTR(E0_, E1_, E2_, E3_, K, A)                                              \
        K##0 = __builtin_amdgcn_readfirstlane(E0_.x); A##0 = __int_as_float(E0_.y); \
        K##1 = __builtin_amdgcn_readfirstlane(E0_.z); A##1 = __int_as_float(E0_.w); \
        K##2 = __builtin_amdgcn_readfirstlane(E1_.x); A##2 = __int_as_float(E1_.y); \
        K##3 = __builtin_amdgcn_readfirstlane(E1_.z); A##3 = __int_as_float(E1_.w); \
        K##4 = __builtin_amdgcn_readfirstlane(E2_.x); A##4 = __int_as_float(E2_.y); \
        K##5 = __builtin_amdgcn_readfirstlane(E2_.z); A##5 = __int_as_float(E2_.w); \
        K##6 = __builtin_amdgcn_readfirstlane(E3_.x); A##6 = __int_as_float(E3_.y); \
        K##7 = __builtin_amdgcn_readfirstlane(E3_.z); A##7 = __int_as_float(E3_.w);

#define ISSUE8(K, U)                                                    \
        U##0 = *(const u32x4*)(m2l + (size_t)K##0 * N_NODES);           \
        U##1 = *(const u32x4*)(m2l + (size_t)K##1 * N_NODES);           \
        U##2 = *(const u32x4*)(m2l + (size_t)K##2 * N_NODES);           \
        U##3 = *(const u32x4*)(m2l + (size_t)K##3 * N_NODES);           \
        U##4 = *(const u32x4*)(m2l + (size_t)K##4 * N_NODES);           \
        U##5 = *(const u32x4*)(m2l + (size_t)K##5 * N_NODES);           \
        U##6 = *(const u32x4*)(m2l + (size_t)K##6 * N_NODES);           \
        U##7 = *(const u32x4*)(m2l + (size_t)K##7 * N_NODES);

#define CONSUME8(U, A)                                                      \
        ACC8(U##0, A##0) ACC8(U##1, A##1) ACC8(U##2, A##2) ACC8(U##3, A##3) \
        ACC8(U##4, A##4) ACC8(U##5, A##5) ACC8(U##6, A##6) ACC8(U##7, A##7)

__global__ __launch_bounds__(128, 3)
void out_kernel(const int* __restrict__ counts, const int2* __restrict__ pairs,
                const unsigned short* __restrict__ m2,
                float* __restrict__ out) {
    __shared__ float ap[2][JTILE];
    int lin = blockIdx.x;
    int tile = lin & 7;
    int jb = tile * JTILE;
    int t = threadIdx.x;
    int w = t >> 6, lane = t & 63;
    int i = 2 * (lin >> 3) + w;
    float* apw = ap[w];
    // TH2 row: issue first (oldest in queue, retired long before epilogue)
    u32x4 um = *(const u32x4*)(m2 + (size_t)i * N_NODES + jb + 8 * lane);
    float4 z4 = make_float4(0.f, 0.f, 0.f, 0.f);
    ((float4*)apw)[lane] = z4;
    ((float4*)apw)[64 + lane] = z4;
    int cnt = min(counts[i * CPAD], RCAP);
    const int2* pi = pairs + i * RCAP;
    // P0 + A scatter into private strip (dups accumulate; cnt excludes pads)
    for (int e = lane; e < cnt; e += 64) {
        int2 p = pi[e];
        int cl = p.x - jb;
        if ((unsigned)cl < (unsigned)JTILE)
            unsafeAtomicAdd(&apw[cl], TH0 + TH1 * __int_as_float(p.y));
    }
    int cnt8 = (cnt + 7) & ~7;
    const unsigned short* m2l = m2 + jb + 8 * lane;
    v4f acc0 = 0.f, acc1 = 0.f;
    const int4* pi4 = (const int4*)pi;

    if (cnt8 > 0) {
        int4 e0, e1, e2, e3, n0, n1, n2, n3;
        int kA0, kA1, kA2, kA3, kA4, kA5, kA6, kA7;
        int kB0, kB1, kB2, kB3, kB4, kB5, kB6, kB7;
        float aA0, aA1, aA2, aA3, aA4, aA5, aA6, aA7;
        float aB0, aB1, aB2, aB3, aB4, aB5, aB6, aB7;
        u32x4 uA0, uA1, uA2, uA3, uA4, uA5, uA6, uA7;
        u32x4 uB0, uB1, uB2, uB3, uB4, uB5, uB6, uB7;

        // prologue: batch0 edges -> extract -> issue uA; prefetch batch1 edges
        e0 = pi4[0]; e1 = pi4[1]; e2 = pi4[2]; e3 = pi4[3];
        EXTR(e0, e1, e2, e3, kA, aA)          // one-time vmcnt(0) stall
        ISSUE8(kA, uA)
        n0 = pi4[4]; n1 = pi4[5]; n2 = pi4[6]; n3 = pi4[7];

        int e = 0;
        for (;;) {
            // phase A: n holds edges for batch e+8; uA holds rows of batch e
            if (e + 8 < cnt8) {
                EXTR(n0, n1, n2, n3, kB, aB)  // edges issued >=1 consume ago
                ISSUE8(kB, uB)
                int nb = (e + 16) >> 1;       // batch e+16 (may overshoot: ok)
                n0 = pi4[nb]; n1 = pi4[nb + 1]; n2 = pi4[nb + 2]; n3 = pi4[nb + 3];
                CONSUME8(uA, aA)              // vmcnt leaves uB+n outstanding
                e += 8;
            } else { CONSUME8(uA, aA) break; }
            // phase B: symmetric
            if (e + 8 < cnt8) {
                EXTR(n0, n1, n2, n3, kA, aA)
                ISSUE8(kA, uA)
                int nb = (e + 16) >> 1;
                n0 = pi4[nb]; n1 = pi4[nb + 1]; n2 = pi4[nb + 2]; n3 = pi4[nb + 3];
                CONSUME8(uB, aB)
                e += 8;
            } else { CONSUME8(uB, aB) break; }
        }
    }

    // epilogue: private strip + TH2*m2[i] + TH3*thr(acc)
    float4 p0 = ((const float4*)apw)[2 * lane];
    float4 p1 = ((const float4*)apw)[2 * lane + 1];
    v4f r0, r1;
    r0.x = p0.x + TH2 * lo16(um.x) + TH3 * ((acc0.x >= EPS) ? acc0.x : 0.0f);
    r0.y = p0.y + TH2 * hi16(um.x) + TH3 * ((acc0.y >= EPS) ? acc0.y : 0.0f);
    r0.z = p0.z + TH2 * lo16(um.y) + TH3 * ((acc0.z >= EPS) ? acc0.z : 0.0f);
    r0.w = p0.w + TH2 * hi16(um.y) + TH3 * ((acc0.w >= EPS) ? acc0.w : 0.0f);
    r1.x = p1.x + TH2 * lo16(um.z) + TH3 * ((acc1.x >= EPS) ? acc1.x : 0.0f);
    r1.y = p1.y + TH2 * hi16(um.z) + TH3 * ((acc1.y >= EPS) ? acc1.y : 0.0f);
    r1.z = p1.z + TH2 * lo16(um.w) + TH3 * ((acc1.z >= EPS) ? acc1.z : 0.0f);
    r1.w = p1.w + TH2 * hi16(um.w) + TH3 * ((acc1.w >= EPS) ? acc1.w : 0.0f);
    float* o = out + (size_t)i * N_NODES + jb + 8 * lane;
    __builtin_nontemporal_store(r0, (v4f*)o);
    __builtin_nontemporal_store(r1, (v4f*)(o + 4));
}

extern "C" void kernel_launch(void* const* d_in, const int* in_sizes, int n_in,
                              void* d_out, int out_size, void* d_ws, size_t ws_size,
                              hipStream_t stream) {
    const int* idx = (const int*)d_in[1];     // [2,E] flat: src then dst
    const float* attr = (const float*)d_in[2];
    int E = in_sizes[1] / 2;

    char* ws = (char*)d_ws;
    int*  counts = (int*)(ws);
    int2* pairs  = (int2*)(ws + (256 << 10));
    unsigned short* m2 = (unsigned short*)(ws + (4 << 20));
    float* out   = (float*)d_out;

    // counts (padded) + pairs contiguous: one memset
    (void)hipMemsetAsync(ws, 0,
                         (256 << 10) + N_NODES * RCAP * sizeof(int2), stream);
    scatter_kernel<<<(E + 255) / 256, 256, 0, stream>>>(idx, attr, E, counts, pairs);
    m2_kernel<<<N_NODES, 256, 0, stream>>>(counts, pairs, m2);
    out_kernel<<<(N_NODES / 2) * NTILES, 128, 0, stream>>>(counts, pairs, m2, out);
}

// Round 3
// 207.226 us; speedup vs baseline: 1.3017x; 1.3017x over previous
//
#include <hip/hip_runtime.h>

#define N_NODES 4096
#define EPS 0.005f
#define TH0 0.4f
#define TH1 0.24f
#define TH2 0.144f
#define TH3 0.0864f
#define JTILE 512
#define NTILES (N_NODES / JTILE)
#define RCAP 80      // fixed per-row slot capacity (mean deg 32, P(>80)~1e-13)
#define CPAD 16      // one counter per 64B line -> no cross-XCD line ping-pong

typedef float v4f __attribute__((ext_vector_type(4)));
typedef unsigned int u32x4 __attribute__((ext_vector_type(4)));

// ws layout (byte offsets):
//   0      counts int[4096*16]         256KB \ one contiguous memset (2816KB)
//   256K   pairs  int2[4096*RCAP]      2.5MB / pads col=0,val=0 -> fma no-op
//   4M     m2     bf16[N*N]            32MB dense thresholded A@A
// NOTE: out_kernel edge prefetch may overshoot a row's 640B pair strip by up
// to 64B (next row / tail pad region, still inside ws) — loaded, never used.

static __device__ __forceinline__ float lo16(unsigned int u) {
    return __uint_as_float(u << 16);
}
static __device__ __forceinline__ float hi16(unsigned int u) {
    return __uint_as_float(u & 0xffff0000u);
}

static __device__ __forceinline__ unsigned short f2bf(float f) {
    union { float f; unsigned int i; } x;
    x.f = f;
    unsigned int r = x.i + 0x7fff + ((x.i >> 16) & 1u);  // RNE; finite >=0
    return (unsigned short)(r >> 16);
}

// one pass: bin edges into fixed-stride packed (col,val) slots
__global__ void scatter_kernel(const int* __restrict__ idx,
                               const float* __restrict__ attr, int E,
                               int* __restrict__ counts, int2* __restrict__ pairs) {
    int e = blockIdx.x * blockDim.x + threadIdx.x;
    if (e < E) {
        int s = idx[e];
        int d = idx[e + E];
        float a = attr[e];
        int pos = atomicAdd(&counts[s * CPAD], 1);
        if (pos < RCAP) pairs[s * RCAP + pos] = make_int2(d, __float_as_int(a));
    }
}

// M2 = thr(A@A) bf16. One block per row, full-row 16KB LDS accumulator.
// 32 groups x 8 lanes; fan-out list walked in 32-slot rounds of 4 INDEPENDENT
// loads (chain depth 4 -> 1). Slots in [fn,RCAP) are zero-pads -> no-op adds.
__global__ __launch_bounds__(256)
void m2_kernel(const int* __restrict__ counts, const int2* __restrict__ pairs,
               unsigned short* __restrict__ m2) {
    __shared__ float acc[N_NODES];
    __shared__ int   kcol[RCAP];
    __shared__ float kval[RCAP];
    __shared__ int   kcnt[RCAP];
    int i = blockIdx.x;
    int t = threadIdx.x;
    float4 z = make_float4(0.f, 0.f, 0.f, 0.f);
    for (int j4 = t; j4 < N_NODES / 4; j4 += 256) ((float4*)acc)[j4] = z;
    int cnt = min(counts[i * CPAD], RCAP);
    if (t < cnt) {
        int2 p = pairs[i * RCAP + t];
        kcol[t] = p.x;
        kval[t] = __int_as_float(p.y);
        kcnt[t] = min(counts[p.x * CPAD], RCAP);
    }
    __syncthreads();
    int gid = t >> 3, gl = t & 7;            // 32 groups x 8 lanes
    int2 zp = make_int2(0, 0);
    for (int q = gid; q < cnt; q += 32) {
        float a = kval[q];
        int fb = kcol[q] * RCAP;
        int fn = kcnt[q];
        for (int f0 = gl; f0 < fn; f0 += 32) {
            int i1 = f0 + 8, i2 = f0 + 16, i3 = f0 + 24;
            // 4 independent loads issued before any atomic; masked -> (0,0)
            int2 p0 = pairs[fb + f0];
            int2 p1 = (i1 < fn) ? pairs[fb + i1] : zp;
            int2 p2 = (i2 < fn) ? pairs[fb + i2] : zp;
            int2 p3 = (i3 < fn) ? pairs[fb + i3] : zp;
            unsafeAtomicAdd(&acc[p0.x], a * __int_as_float(p0.y));
            unsafeAtomicAdd(&acc[p1.x], a * __int_as_float(p1.y));
            unsafeAtomicAdd(&acc[p2.x], a * __int_as_float(p2.y));
            unsafeAtomicAdd(&acc[p3.x], a * __int_as_float(p3.y));
        }
    }
    __syncthreads();
    size_t rb = (size_t)i * N_NODES;
    for (int j4 = t; j4 < N_NODES / 4; j4 += 256) {
        float4 v = ((const float4*)acc)[j4];
        ushort4 r;
        r.x = (v.x >= EPS) ? f2bf(v.x) : (unsigned short)0;
        r.y = (v.y >= EPS) ? f2bf(v.y) : (unsigned short)0;
        r.z = (v.z >= EPS) ? f2bf(v.z) : (unsigned short)0;
        r.w = (v.w >= EPS) ? f2bf(v.w) : (unsigned short)0;
        ((ushort4*)(m2 + rb))[j4] = r;
    }
}

// out[i, jb:jb+512] = TH0*P0 + TH1*A + TH2*M2 + TH3*thr(A @ M2)  — fused.
// Minimal-state software pipeline: ONE edge-quad prefetch buffer (n0..n3,
// one batch ahead) + U ping-pong (uA/uB). Steady state has zero exposed
// latency: EXTR waits on edges issued a full consume (256cy) earlier;
// CONSUME8 waits counted vmcnt on U issued one phase earlier. ~120 live
// VGPRs — so NO second launch_bounds arg: (128,3) budgeted 84 VGPRs/wave
// (6 waves/EU) and spilled ~600MB/dispatch to scratch (R1/R2 post-mortem).
#define ACC8(uu, aa)                                \
        acc0.x = fmaf(aa, lo16(uu.x), acc0.x);      \
        acc0.y = fmaf(aa, hi16(uu.x), acc0.y);      \
        acc0.z = fmaf(aa, lo16(uu.y), acc0.z);      \
        acc0.w = fmaf(aa, hi16(uu.y), acc0.w);      \
        acc1.x = fmaf(aa, lo16(uu.z), acc1.x);      \
        acc1.y = fmaf(aa, hi16(uu.z), acc1.y);      \
        acc1.z = fmaf(aa, lo16(uu.w), acc1.z);      \
        acc1.w = fmaf(aa, hi16(uu.w), acc1.w);

#define EXTR(E0_, E1_, E2_, E3_, K, A)                                              \
        K##0 = __builtin_amdgcn_readfirstlane(E0_.x); A##0 = __int_as_float(E0_.y); \
        K##1 = __builtin_amdgcn_readfirstlane(E0_.z); A##1 = __int_as_float(E0_.w); \
        K##2 = __builtin_amdgcn_readfirstlane(E1_.x); A##2 = __int_as_float(E1_.y); \
        K##3 = __builtin_amdgcn_readfirstlane(E1_.z); A##3 = __int_as_float(E1_.w); \
        K##4 = __builtin_amdgcn_readfirstlane(E2_.x); A##4 = __int_as_float(E2_.y); \
        K##5 = __builtin_amdgcn_readfirstlane(E2_.z); A##5 = __int_as_float(E2_.w); \
        K##6 = __builtin_amdgcn_readfirstlane(E3_.x); A##6 = __int_as_float(E3_.y); \
        K##7 = __builtin_amdgcn_readfirstlane(E3_.z); A##7 = __int_as_float(E3_.w);

#define ISSUE8(K, U)                                                    \
        U##0 = *(const u32x4*)(m2l + (size_t)K##0 * N_NODES);           \
        U##1 = *(const u32x4*)(m2l + (size_t)K##1 * N_NODES);           \
        U##2 = *(const u32x4*)(m2l + (size_t)K##2 * N_NODES);           \
        U##3 = *(const u32x4*)(m2l + (size_t)K##3 * N_NODES);           \
        U##4 = *(const u32x4*)(m2l + (size_t)K##4 * N_NODES);           \
        U##5 = *(const u32x4*)(m2l + (size_t)K##5 * N_NODES);           \
        U##6 = *(const u32x4*)(m2l + (size_t)K##6 * N_NODES);           \
        U##7 = *(const u32x4*)(m2l + (size_t)K##7 * N_NODES);

#define CONSUME8(U, A)                                                      \
        ACC8(U##0, A##0) ACC8(U##1, A##1) ACC8(U##2, A##2) ACC8(U##3, A##3) \
        ACC8(U##4, A##4) ACC8(U##5, A##5) ACC8(U##6, A##6) ACC8(U##7, A##7)

__global__ __launch_bounds__(128)
void out_kernel(const int* __restrict__ counts, const int2* __restrict__ pairs,
                const unsigned short* __restrict__ m2,
                float* __restrict__ out) {
    __shared__ float ap[2][JTILE];
    int lin = blockIdx.x;
    int tile = lin & 7;
    int jb = tile * JTILE;
    int t = threadIdx.x;
    int w = t >> 6, lane = t & 63;
    int i = 2 * (lin >> 3) + w;
    float* apw = ap[w];
    // TH2 row: issue first (oldest in queue, retired long before epilogue)
    u32x4 um = *(const u32x4*)(m2 + (size_t)i * N_NODES + jb + 8 * lane);
    float4 z4 = make_float4(0.f, 0.f, 0.f, 0.f);
    ((float4*)apw)[lane] = z4;
    ((float4*)apw)[64 + lane] = z4;
    int cnt = min(counts[i * CPAD], RCAP);
    const int2* pi = pairs + i * RCAP;
    // P0 + A scatter into private strip (dups accumulate; cnt excludes pads)
    for (int e = lane; e < cnt; e += 64) {
        int2 p = pi[e];
        int cl = p.x - jb;
        if ((unsigned)cl < (unsigned)JTILE)
            unsafeAtomicAdd(&apw[cl], TH0 + TH1 * __int_as_float(p.y));
    }
    int cnt8 = (cnt + 7) & ~7;
    const unsigned short* m2l = m2 + jb + 8 * lane;
    v4f acc0 = 0.f, acc1 = 0.f;
    const int4* pi4 = (const int4*)pi;

    if (cnt8 > 0) {
        int4 e0, e1, e2, e3, n0, n1, n2, n3;
        int kA0, kA1, kA2, kA3, kA4, kA5, kA6, kA7;
        int kB0, kB1, kB2, kB3, kB4, kB5, kB6, kB7;
        float aA0, aA1, aA2, aA3, aA4, aA5, aA6, aA7;
        float aB0, aB1, aB2, aB3, aB4, aB5, aB6, aB7;
        u32x4 uA0, uA1, uA2, uA3, uA4, uA5, uA6, uA7;
        u32x4 uB0, uB1, uB2, uB3, uB4, uB5, uB6, uB7;

        // prologue: batch0 edges -> extract -> issue uA; prefetch batch1 edges
        e0 = pi4[0]; e1 = pi4[1]; e2 = pi4[2]; e3 = pi4[3];
        EXTR(e0, e1, e2, e3, kA, aA)          // one-time vmcnt(0) stall
        ISSUE8(kA, uA)
        n0 = pi4[4]; n1 = pi4[5]; n2 = pi4[6]; n3 = pi4[7];

        int e = 0;
        for (;;) {
            // phase A: n holds edges for batch e+8; uA holds rows of batch e
            if (e + 8 < cnt8) {
                EXTR(n0, n1, n2, n3, kB, aB)  // edges issued >=1 consume ago
                ISSUE8(kB, uB)
                int nb = (e + 16) >> 1;       // batch e+16 (may overshoot: ok)
                n0 = pi4[nb]; n1 = pi4[nb + 1]; n2 = pi4[nb + 2]; n3 = pi4[nb + 3];
                CONSUME8(uA, aA)              // vmcnt leaves uB+n outstanding
                e += 8;
            } else { CONSUME8(uA, aA) break; }
            // phase B: symmetric
            if (e + 8 < cnt8) {
                EXTR(n0, n1, n2, n3, kA, aA)
                ISSUE8(kA, uA)
                int nb = (e + 16) >> 1;
                n0 = pi4[nb]; n1 = pi4[nb + 1]; n2 = pi4[nb + 2]; n3 = pi4[nb + 3];
                CONSUME8(uB, aB)
                e += 8;
            } else { CONSUME8(uB, aB) break; }
        }
    }

    // epilogue: private strip + TH2*m2[i] + TH3*thr(acc)
    float4 p0 = ((const float4*)apw)[2 * lane];
    float4 p1 = ((const float4*)apw)[2 * lane + 1];
    v4f r0, r1;
    r0.x = p0.x + TH2 * lo16(um.x) + TH3 * ((acc0.x >= EPS) ? acc0.x : 0.0f);
    r0.y = p0.y + TH2 * hi16(um.x) + TH3 * ((acc0.y >= EPS) ? acc0.y : 0.0f);
    r0.z = p0.z + TH2 * lo16(um.y) + TH3 * ((acc0.z >= EPS) ? acc0.z : 0.0f);
    r0.w = p0.w + TH2 * hi16(um.y) + TH3 * ((acc0.w >= EPS) ? acc0.w : 0.0f);
    r1.x = p1.x + TH2 * lo16(um.z) + TH3 * ((acc1.x >= EPS) ? acc1.x : 0.0f);
    r1.y = p1.y + TH2 * hi16(um.z) + TH3 * ((acc1.y >= EPS) ? acc1.y : 0.0f);
    r1.z = p1.z + TH2 * lo16(um.w) + TH3 * ((acc1.z >= EPS) ? acc1.z : 0.0f);
    r1.w = p1.w + TH2 * hi16(um.w) + TH3 * ((acc1.w >= EPS) ? acc1.w : 0.0f);
    float* o = out + (size_t)i * N_NODES + jb + 8 * lane;
    __builtin_nontemporal_store(r0, (v4f*)o);
    __builtin_nontemporal_store(r1, (v4f*)(o + 4));
}

extern "C" void kernel_launch(void* const* d_in, const int* in_sizes, int n_in,
                              void* d_out, int out_size, void* d_ws, size_t ws_size,
                              hipStream_t stream) {
    const int* idx = (const int*)d_in[1];     // [2,E] flat: src then dst
    const float* attr = (const float*)d_in[2];
    int E = in_sizes[1] / 2;

    char* ws = (char*)d_ws;
    int*  counts = (int*)(ws);
    int2* pairs  = (int2*)(ws + (256 << 10));
    unsigned short* m2 = (unsigned short*)(ws + (4 << 20));
    float* out   = (float*)d_out;

    // counts (padded) + pairs contiguous: one memset
    (void)hipMemsetAsync(ws, 0,
                         (256 << 10) + N_NODES * RCAP * sizeof(int2), stream);
    scatter_kernel<<<(E + 255) / 256, 256, 0, stream>>>(idx, attr, E, counts, pairs);
    m2_kernel<<<N_NODES, 256, 0, stream>>>(counts, pairs, m2);
    out_kernel<<<(N_NODES / 2) * NTILES, 128, 0, stream>>>(counts, pairs, m2, out);
}